// Round 2
// baseline (1675.490 us; speedup 1.0000x reference)
//
#include <hip/hip_runtime.h>

#define DEVINLINE __device__ __forceinline__

constexpr int HID = 128;
constexpr int NSPLIT = 4;
constexpr int CAND = 16;    // candidates kept per split per row (screening margin)
constexpr int KTH  = 10;    // per-thread screening list length

DEVINLINE bool lex_lt(float d1, int i1, float d2, int i2) {
    return (d1 < d2) || ((d1 == d2) && (i1 < i2));
}

// Insert (d, j) into an ascending sorted top-K list kept in registers.
// Fully unrolled compare-swap chain: every index is compile-time constant.
template<int K>
DEVINLINE void topk_insert(float (&bd)[K], int (&bi)[K], float d, int j) {
    if (!lex_lt(d, j, bd[K-1], bi[K-1])) return;
    float cd = d; int ci = j;
#pragma unroll
    for (int p = 0; p < K; ++p) {
        const bool lt = lex_lt(cd, ci, bd[p], bi[p]);
        const float sd = bd[p]; const int si = bi[p];
        bd[p] = lt ? cd : sd;  bi[p] = lt ? ci : si;
        cd = lt ? sd : cd;     ci = lt ? si : ci;
    }
}

// ---------------- squared norms ----------------
template<int D>
__global__ void sqnorm_kernel(const float* __restrict__ X, float* __restrict__ sq, int n) {
    const int i = blockIdx.x * 256 + threadIdx.x;
    if (i >= n) return;
    const float4* row = (const float4*)(X + (size_t)i * D);
    float s = 0.f;
#pragma unroll
    for (int u = 0; u < D / 4; ++u) {
        const float4 v = row[u];
        s += v.x * v.x + v.y * v.y + v.z * v.z + v.w * v.w;
    }
    sq[i] = s;
}

// ---------------- fused distance-GEMM + streaming top-k screening ----------------
// Grid: (ceil(n/32), NSPLIT). Block: 256.
// Each WG: 32 query rows vs one contiguous column range; emits per-split
// top-CAND candidate INDICES (fp32 screening order) for fp64 rescoring.
template<int D>
__global__ __launch_bounds__(256)
void knn_kernel(const float* __restrict__ X, const float* __restrict__ sq,
                int* __restrict__ cand_i, int n, int cols_per_split) {
    constexpr int BM = 32, BN = 128, DC = 64;
    constexpr int NCH = D / DC;
    constexpr size_t BYTES_B = (size_t)DC * BN * 4;       // 32 KB
    constexpr size_t BYTES_A = (size_t)D * BM * 4;        // 8/16 KB
    constexpr size_t BYTES_SQ = (size_t)BN * 4;
    constexpr size_t BYTES_M = (size_t)2 * BM * 16 * KTH * 4;   // 40 KB merge scratch
    constexpr size_t SMEM_SZ = (BYTES_B + BYTES_A + BYTES_SQ > BYTES_M)
                                   ? (BYTES_B + BYTES_A + BYTES_SQ) : BYTES_M;
    __shared__ __align__(16) char smem[SMEM_SZ];
    float* Blds  = (float*)smem;                       // [DC][BN]  (d-major)
    float* Alds  = (float*)(smem + BYTES_B);           // [D][BM]
    float* sqlds = (float*)(smem + BYTES_B + BYTES_A); // [BN]

    const int tid = threadIdx.x;
    const int cg  = tid & 15;   // column group 0..15 (owns cols cg+16e)
    const int rg  = tid >> 4;   // row group 0..15 (owns 2 rows)
    const int row0 = blockIdx.x * BM;
    const int sp   = blockIdx.y;
    const int c_begin = sp * cols_per_split;
    const int c_end   = min(c_begin + cols_per_split, n);

    // Stage A tile (all D dims of the 32 query rows), transposed to [d][r].
    {
        const int rr = tid & 31;
        const int g  = tid >> 5;            // 0..7
        constexpr int DG = D / 8;           // dims per group
        const int r = row0 + rr;
        const bool ok = r < n;
#pragma unroll
        for (int u = 0; u < DG / 4; ++u) {
            const int d0 = g * DG + u * 4;
            float4 v = ok ? *(const float4*)(X + (size_t)r * D + d0)
                          : make_float4(0.f, 0.f, 0.f, 0.f);
            Alds[(d0 + 0) * BM + rr] = v.x;
            Alds[(d0 + 1) * BM + rr] = v.y;
            Alds[(d0 + 2) * BM + rr] = v.z;
            Alds[(d0 + 3) * BM + rr] = v.w;
        }
    }

    const int r0 = row0 + rg * 2;
    const int r1 = r0 + 1;
    const float sq0 = (r0 < n) ? sq[r0] : 0.f;
    const float sq1 = (r1 < n) ? sq[r1] : 0.f;

    float bd0[KTH], bd1[KTH]; int bi0[KTH], bi1[KTH];
#pragma unroll
    for (int p = 0; p < KTH; ++p) {
        bd0[p] = __builtin_inff(); bd1[p] = __builtin_inff();
        bi0[p] = 0x7fffffff;       bi1[p] = 0x7fffffff;
    }

    for (int ct = c_begin; ct < c_end; ct += BN) {
        float acc0[8], acc1[8];
#pragma unroll
        for (int e = 0; e < 8; ++e) { acc0[e] = 0.f; acc1[e] = 0.f; }

#pragma unroll
        for (int kc = 0; kc < NCH; ++kc) {
            __syncthreads();   // protect previous chunk reads / sqlds
            // Stage B chunk transposed: Blds[dd][cc] = X[ct+cc][kc*DC+dd]
            {
                const int cc = tid & 127;
                const int hf = tid >> 7;       // 0..1
                const int c  = ct + cc;
                const bool ok = c < c_end;
                const float* src = X + (size_t)c * D + kc * DC + hf * (DC / 2);
#pragma unroll
                for (int u = 0; u < DC / 8; ++u) {
                    float4 v = ok ? *(const float4*)(src + u * 4)
                                  : make_float4(0.f, 0.f, 0.f, 0.f);
                    const int d0 = hf * (DC / 2) + u * 4;
                    Blds[(d0 + 0) * BN + cc] = v.x;
                    Blds[(d0 + 1) * BN + cc] = v.y;
                    Blds[(d0 + 2) * BN + cc] = v.z;
                    Blds[(d0 + 3) * BN + cc] = v.w;
                }
                if (kc == 0 && tid < BN) {
                    const int c2 = ct + tid;
                    sqlds[tid] = (c2 < c_end) ? sq[c2] : 0.f;
                }
            }
            __syncthreads();

#pragma unroll 4
            for (int dd = 0; dd < DC; ++dd) {
                const int d = kc * DC + dd;
                const float a0 = Alds[d * BM + rg * 2];
                const float a1 = Alds[d * BM + rg * 2 + 1];
#pragma unroll
                for (int e = 0; e < 8; ++e) {
                    const float bv = Blds[dd * BN + cg + 16 * e];
                    acc0[e] = fmaf(a0, bv, acc0[e]);
                    acc1[e] = fmaf(a1, bv, acc1[e]);
                }
            }
        }

        // streaming top-k update for this column tile
#pragma unroll
        for (int e = 0; e < 8; ++e) {
            const int j = ct + cg + 16 * e;
            if (j >= c_end) continue;
            const float sqc = sqlds[cg + 16 * e];
            const float d20 = sq0 + sqc - 2.f * acc0[e];
            const float d21 = sq1 + sqc - 2.f * acc1[e];
            if (j != r0) topk_insert<KTH>(bd0, bi0, d20, j);
            if (j != r1) topk_insert<KTH>(bd1, bi1, d21, j);
        }
    }

    // Merge the 16 column-group lists per row (via LDS, aliasing the tiles).
    __syncthreads();
    float* md = (float*)smem;                                 // [BM][16][KTH]
    int*   mi = (int*)(smem + (size_t)BM * 16 * KTH * 4);     // [BM][16][KTH]
#pragma unroll
    for (int p = 0; p < KTH; ++p) {
        md[((rg * 2 + 0) * 16 + cg) * KTH + p] = bd0[p];
        mi[((rg * 2 + 0) * 16 + cg) * KTH + p] = bi0[p];
        md[((rg * 2 + 1) * 16 + cg) * KTH + p] = bd1[p];
        mi[((rg * 2 + 1) * 16 + cg) * KTH + p] = bi1[p];
    }
    __syncthreads();
    if (tid < BM) {
        float fd[CAND]; int fi[CAND];
#pragma unroll
        for (int p = 0; p < CAND; ++p) { fd[p] = __builtin_inff(); fi[p] = 0x7fffffff; }
        for (int c = 0; c < 16; ++c) {
#pragma unroll
            for (int p = 0; p < KTH; ++p) {
                topk_insert<CAND>(fd, fi, md[(tid * 16 + c) * KTH + p],
                                          mi[(tid * 16 + c) * KTH + p]);
            }
        }
        const int row = row0 + tid;
        if (row < n) {
#pragma unroll
            for (int p = 0; p < CAND; ++p)
                cand_i[((size_t)sp * n + row) * CAND + p] = fi[p];
        }
    }
}

// ---------------- fp64 rescore + exact top-K select ----------------
// One wave per row; lane l handles candidate (split l/16, slot l%16).
// d2 = sum_d (x_i[d]-x_j[d])^2 in fp64 -> exact ranking vs the reference.
template<int D, int K>
__global__ __launch_bounds__(256)
void rescore_kernel(const float* __restrict__ X, const int* __restrict__ cand_i,
                    int* __restrict__ idx_out, int n) {
    const int lane = threadIdx.x & 63;
    const int row  = blockIdx.x * 4 + (threadIdx.x >> 6);
    if (row >= n) return;
    const int sp = lane >> 4, slot = lane & 15;
    int j = cand_i[((size_t)sp * n + row) * CAND + slot];
    double d2 = 1e300;
    if (j < n) {
        const float4* xi = (const float4*)(X + (size_t)row * D);
        const float4* xj = (const float4*)(X + (size_t)j * D);
        double s = 0.0;
#pragma unroll
        for (int u = 0; u < D / 4; ++u) {
            const float4 a = xi[u];
            const float4 b = xj[u];
            double t;
            t = (double)a.x - (double)b.x; s = fma(t, t, s);
            t = (double)a.y - (double)b.y; s = fma(t, t, s);
            t = (double)a.z - (double)b.z; s = fma(t, t, s);
            t = (double)a.w - (double)b.w; s = fma(t, t, s);
        }
        d2 = s;
    } else {
        j = 0x7fffffff;
    }

#pragma unroll
    for (int p = 0; p < K; ++p) {
        double md = d2; int mj = j;
#pragma unroll
        for (int off = 32; off >= 1; off >>= 1) {
            const double od = __shfl_xor(md, off, 64);
            const int    oj = __shfl_xor(mj, off, 64);
            if ((od < md) || ((od == md) && (oj < mj))) { md = od; mj = oj; }
        }
        if (lane == 0) idx_out[(size_t)row * K + p] = mj;
        if (j == mj) { d2 = 1e300; j = 0x7fffffff; }   // eliminate winner
    }
}

// ---------------- T = X @ W^T  (no bias; bias folded into gather-max) ----------------
template<int D>
__global__ __launch_bounds__(256)
void lin_kernel(const float* __restrict__ X, const float* __restrict__ W,
                float* __restrict__ T, int n) {
    constexpr int PB = 16;
    __shared__ float Wlds[D * HID];   // [d][h] transposed
    __shared__ float Xlds[PB * D];    // [p][d]
    const int tid = threadIdx.x;
    const int p0 = blockIdx.x * PB;

    {   // stage W transposed
        const int h  = tid & 127;
        const int hf = tid >> 7;
#pragma unroll
        for (int u = 0; u < D / 8; ++u) {
            const int d0 = hf * (D / 2) + u * 4;
            const float4 v = *(const float4*)(W + (size_t)h * D + d0);
            Wlds[(d0 + 0) * HID + h] = v.x;
            Wlds[(d0 + 1) * HID + h] = v.y;
            Wlds[(d0 + 2) * HID + h] = v.z;
            Wlds[(d0 + 3) * HID + h] = v.w;
        }
    }
    {   // stage X rows
        const int rr = tid & 15;
        const int g  = tid >> 4;            // 0..15
        constexpr int DG = D / 16;          // 4 or 8
        const int p = p0 + rr;
        const bool ok = p < n;
#pragma unroll
        for (int u = 0; u < DG / 4; ++u) {
            const int d0 = g * DG + u * 4;
            const float4 v = ok ? *(const float4*)(X + (size_t)p * D + d0)
                                : make_float4(0.f, 0.f, 0.f, 0.f);
            *(float4*)(&Xlds[rr * D + d0]) = v;
        }
    }
    __syncthreads();

    const int pp = tid >> 4;   // 0..15
    const int hh = tid & 15;
    float acc[8];
#pragma unroll
    for (int e = 0; e < 8; ++e) acc[e] = 0.f;
#pragma unroll 4
    for (int d = 0; d < D; ++d) {
        const float xa = Xlds[pp * D + d];
#pragma unroll
        for (int e = 0; e < 8; ++e)
            acc[e] = fmaf(xa, Wlds[d * HID + hh + 16 * e], acc[e]);
    }
    const int p = p0 + pp;
    if (p < n) {
#pragma unroll
        for (int e = 0; e < 8; ++e)
            T[(size_t)p * HID + hh + 16 * e] = acc[e];
    }
}

// ---------------- h[i,:] = max_j T[idx_j,:] - T[i,:] + b ----------------
template<int K>
__global__ void gathermax_kernel(const float* __restrict__ T, const int* __restrict__ idx,
                                 const float* __restrict__ b, float* __restrict__ out, int n) {
    const int i = blockIdx.x;
    const int h = threadIdx.x;   // 128
    float m = -__builtin_inff();
#pragma unroll
    for (int t = 0; t < K; ++t) {
        const int j = idx[(size_t)i * K + t];   // uniform across block, L1-served
        m = fmaxf(m, T[(size_t)j * HID + h]);
    }
    out[(size_t)i * HID + h] = m - T[(size_t)i * HID + h] + b[h];
}

// ---------------- out = h2 @ Wl^T + bl ----------------
__global__ void final_kernel(const float* __restrict__ h2, const float* __restrict__ Wl,
                             const float* __restrict__ bl, float* __restrict__ out, int n) {
    const int t = blockIdx.x * 256 + threadIdx.x;
    const int i = t >> 4;
    const int c = t & 15;
    if (i >= n || c >= 10) return;
    const float* hr = h2 + (size_t)i * HID;
    const float* wr = Wl + (size_t)c * HID;
    float s = 0.f;
#pragma unroll 4
    for (int d = 0; d < HID; ++d) s = fmaf(hr[d], wr[d], s);
    out[(size_t)i * 10 + c] = s + bl[c];
}

extern "C" void kernel_launch(void* const* d_in, const int* in_sizes, int n_in,
                              void* d_out, int out_size, void* d_ws, size_t ws_size,
                              hipStream_t stream) {
    const float* x  = (const float*)d_in[0];
    const float* W1 = (const float*)d_in[1];
    const float* b1 = (const float*)d_in[2];
    const float* W2 = (const float*)d_in[3];
    const float* b2 = (const float*)d_in[4];
    const float* Wl = (const float*)d_in[5];
    const float* bl = (const float*)d_in[6];
    float* out = (float*)d_out;
    const int n = in_sizes[0] / 64;   // 10000
    constexpr int K1 = 5, K2 = 10;

    char* ws = (char*)d_ws;
    size_t off = 0;
    auto alloc = [&](size_t bytes) -> void* {
        void* p = ws + off;
        off = (off + bytes + 255) & ~(size_t)255;
        return p;
    };
    float* T1  = (float*)alloc((size_t)n * HID * 4);
    float* h1b = (float*)alloc((size_t)n * HID * 4);
    float* T2  = (float*)alloc((size_t)n * HID * 4);
    float* h2b = (float*)alloc((size_t)n * HID * 4);
    float* sqx = (float*)alloc((size_t)n * 4);
    float* sqh = (float*)alloc((size_t)n * 4);
    int*   idx1 = (int*)alloc((size_t)n * K1 * 4);
    int*   idx2 = (int*)alloc((size_t)n * K2 * 4);
    int*   ci  = (int*)alloc((size_t)NSPLIT * n * CAND * 4);

    const int cps = (n + NSPLIT - 1) / NSPLIT;
    const int rbs = (n + 31) / 32;

    // ---- layer 1 ----
    sqnorm_kernel<64><<<(n + 255) / 256, 256, 0, stream>>>(x, sqx, n);
    knn_kernel<64><<<dim3(rbs, NSPLIT), 256, 0, stream>>>(x, sqx, ci, n, cps);
    rescore_kernel<64, K1><<<(n + 3) / 4, 256, 0, stream>>>(x, ci, idx1, n);
    lin_kernel<64><<<(n + 15) / 16, 256, 0, stream>>>(x, W1, T1, n);
    gathermax_kernel<K1><<<n, HID, 0, stream>>>(T1, idx1, b1, h1b, n);

    // ---- layer 2 ----
    sqnorm_kernel<HID><<<(n + 255) / 256, 256, 0, stream>>>(h1b, sqh, n);
    knn_kernel<HID><<<dim3(rbs, NSPLIT), 256, 0, stream>>>(h1b, sqh, ci, n, cps);
    rescore_kernel<HID, K2><<<(n + 3) / 4, 256, 0, stream>>>(h1b, ci, idx2, n);
    lin_kernel<HID><<<(n + 15) / 16, 256, 0, stream>>>(h1b, W2, T2, n);
    gathermax_kernel<K2><<<n, HID, 0, stream>>>(T2, idx2, b2, h2b, n);

    // ---- head ----
    final_kernel<<<(n * 16 + 255) / 256, 256, 0, stream>>>(h2b, Wl, bl, out, n);
}

// Round 3
// 1318.521 us; speedup vs baseline: 1.2707x; 1.2707x over previous
//
#include <hip/hip_runtime.h>

#define DEVINLINE __device__ __forceinline__

typedef unsigned short u16;
typedef __attribute__((ext_vector_type(8))) short short8v;
typedef __attribute__((ext_vector_type(4))) float float4v;

constexpr int HID = 128;
constexpr int NSPLIT = 8;
constexpr int CAND = 16;    // candidates kept per split per row
constexpr int KTH  = 16;    // per-lane screening list length

DEVINLINE bool lex_lt(float d1, int i1, float d2, int i2) {
    return (d1 < d2) || ((d1 == d2) && (i1 < i2));
}

template<int K>
DEVINLINE void topk_insert(float (&bd)[K], int (&bi)[K], float d, int j) {
    if (!lex_lt(d, j, bd[K-1], bi[K-1])) return;
    float cd = d; int ci = j;
#pragma unroll
    for (int p = 0; p < K; ++p) {
        const bool lt = lex_lt(cd, ci, bd[p], bi[p]);
        const float sd = bd[p]; const int si = bi[p];
        bd[p] = lt ? cd : sd;  bi[p] = lt ? ci : si;
        cd = lt ? sd : cd;     ci = lt ? si : ci;
    }
}

DEVINLINE void gld16(const void* g, void* l) {
    __builtin_amdgcn_global_load_lds((const __attribute__((address_space(1))) unsigned int*)g,
                                     (__attribute__((address_space(3))) unsigned int*)l, 16, 0, 0);
}
DEVINLINE void gld4(const void* g, void* l) {
    __builtin_amdgcn_global_load_lds((const __attribute__((address_space(1))) unsigned int*)g,
                                     (__attribute__((address_space(3))) unsigned int*)l, 4, 0, 0);
}

DEVINLINE u16 f2bf(float x) {
    unsigned u = __float_as_uint(x);
    return (u16)((u + 0x7fffu + ((u >> 16) & 1u)) >> 16);
}
DEVINLINE float bf2f(u16 h) { return __uint_as_float(((unsigned)h) << 16); }

// ---------------- squared norms (exact fp32 from original data) ----------------
template<int D>
__global__ void sqnorm_kernel(const float* __restrict__ X, float* __restrict__ sq, int n) {
    const int i = blockIdx.x * 256 + threadIdx.x;
    if (i >= n) return;
    const float4* row = (const float4*)(X + (size_t)i * D);
    float s = 0.f;
#pragma unroll
    for (int u = 0; u < D / 4; ++u) {
        const float4 v = row[u];
        s += v.x * v.x + v.y * v.y + v.z * v.z + v.w * v.w;
    }
    sq[i] = s;
}

// ---------------- split fp32 -> bf16 hi + lo ----------------
__global__ void split_bf16_kernel(const float* __restrict__ X, u16* __restrict__ hi,
                                  u16* __restrict__ lo, int total4) {
    const int i = blockIdx.x * 256 + threadIdx.x;
    if (i >= total4) return;
    const float4 v = ((const float4*)X)[i];
    float xs[4] = {v.x, v.y, v.z, v.w};
    u16 h4[4], l4[4];
#pragma unroll
    for (int e = 0; e < 4; ++e) {
        const u16 h = f2bf(xs[e]);
        h4[e] = h;
        l4[e] = f2bf(xs[e] - bf2f(h));
    }
    ushort4 hv = {h4[0], h4[1], h4[2], h4[3]};
    ushort4 lv = {l4[0], l4[1], l4[2], l4[3]};
    ((ushort4*)hi)[i] = hv;
    ((ushort4*)lo)[i] = lv;
}

// ---------------- MFMA distance screening ----------------
// Output transposed: C[db_row][query]. WG = 4 waves; wave w owns 16 queries
// (col = lane&15). Queries in registers; db tiles double-buffered in LDS via
// global_load_lds with pre-swizzled global source (rule #21); frag reads are
// XOR-swizzled ds_read_b128 (2-way max -> free). Split-bf16 3-MFMA per K-step
// emulates fp32 dot. Per-lane top-KTH list; 4-lane merge -> per-split CAND.
template<int D>
__global__ __launch_bounds__(256)
void knn_mfma_kernel(const u16* __restrict__ Xhi, const u16* __restrict__ Xlo,
                     const float* __restrict__ sq, int* __restrict__ cand,
                     int n, int cps) {
    constexpr int QB = 64;
    constexpr int MB = (D == 128) ? 48 : 64;   // db rows per tile (LDS budget)
    constexpr int NMI = MB / 16;
    constexpr int KS = D / 32;                 // K-steps of 32
    constexpr int SLOTS = D / 8;               // 16B slots per row
    constexpr int TS = MB * SLOTS;             // slots per (hi or lo) tile
    constexpr int TB = TS * 16;                // bytes per tile
    constexpr int BUFB = 2 * TB + 256;         // hi + lo + sq
    constexpr int SI = (2 * TS) / 256;         // gload_lds instrs per thread
    constexpr int MRG = 256 * KTH * 8;
    constexpr int SMEM = (2 * BUFB > MRG) ? 2 * BUFB : MRG;
    __shared__ __align__(16) char smem[SMEM];

    const int tid   = threadIdx.x;
    const int lane  = tid & 63;
    const int wid   = tid >> 6;
    const int lrow  = lane & 15;
    const int lhalf = lane >> 4;   // 0..3 (k-group / acc row group)

    const int q0   = blockIdx.x * QB;
    const int sp   = blockIdx.y;
    const int rbeg = sp * cps;
    const int rend = min(rbeg + cps, n);
    const int nt   = (rend - rbeg + MB - 1) / MB;

    // ---- query fragments + sq (registers, once) ----
    const int q  = q0 + wid * 16 + lrow;
    const int qc = min(q, n - 1);
    short8v qhi[KS], qlo[KS];
#pragma unroll
    for (int ks = 0; ks < KS; ++ks) {
        const int ksl = ks * 4 + lhalf;
        qhi[ks] = *(const short8v*)(Xhi + (size_t)qc * D + ksl * 8);
        qlo[ks] = *(const short8v*)(Xlo + (size_t)qc * D + ksl * 8);
    }
    const float sqq = sq[qc];

    // ---- staging constants (swizzle applied to GLOBAL source) ----
    int srow[SI], soff[SI]; bool sislo[SI];
#pragma unroll
    for (int it = 0; it < SI; ++it) {
        const int gs = (it * 4 + wid) * 64 + lane;
        const bool islo = gs >= TS;
        const int s   = islo ? gs - TS : gs;
        const int row = s / SLOTS;
        const int psl = s % SLOTS;
        const int ksl = (psl & ~7) | ((psl ^ row) & 7);   // involution
        srow[it] = row; soff[it] = ksl * 8; sislo[it] = islo;
    }

    float bd[KTH]; int bi[KTH];
#pragma unroll
    for (int p = 0; p < KTH; ++p) { bd[p] = __builtin_inff(); bi[p] = 0x7fffffff; }

    auto stage = [&](int t, int b) {
        char* buf = smem + b * BUFB;
        const int row0 = rbeg + t * MB;
#pragma unroll
        for (int it = 0; it < SI; ++it) {
            const int grow = min(row0 + srow[it], rend - 1);
            const u16* src = (sislo[it] ? Xlo : Xhi) + (size_t)grow * D + soff[it];
            gld16(src, buf + (it * 4 + wid) * 1024);
        }
        if (wid == 0) {
            const int grow = min(row0 + lane, rend - 1);
            gld4(sq + grow, buf + 2 * TB);
        }
    };

    auto compute = [&](int t, int b) {
        const char* buf = smem + b * BUFB;
        const u16* hp = (const u16*)buf;
        const u16* lp = (const u16*)(buf + TB);
        const float* sql = (const float*)(buf + 2 * TB);
        const int row0 = rbeg + t * MB;

        float4v acc[NMI];
#pragma unroll
        for (int mi = 0; mi < NMI; ++mi) acc[mi] = (float4v){0.f, 0.f, 0.f, 0.f};

#pragma unroll
        for (int ks = 0; ks < KS; ++ks) {
#pragma unroll
            for (int mi = 0; mi < NMI; ++mi) {
                const int row = mi * 16 + lrow;
                const int ksl = ks * 4 + lhalf;
                const int pk  = (ksl & ~7) | ((ksl ^ row) & 7);
                const size_t off = (size_t)row * (SLOTS * 8) + pk * 8;
                const short8v ah = *(const short8v*)(hp + off);
                const short8v al = *(const short8v*)(lp + off);
                acc[mi] = __builtin_amdgcn_mfma_f32_16x16x32_bf16(ah, qhi[ks], acc[mi], 0, 0, 0);
                acc[mi] = __builtin_amdgcn_mfma_f32_16x16x32_bf16(ah, qlo[ks], acc[mi], 0, 0, 0);
                acc[mi] = __builtin_amdgcn_mfma_f32_16x16x32_bf16(al, qhi[ks], acc[mi], 0, 0, 0);
            }
        }
#pragma unroll
        for (int mi = 0; mi < NMI; ++mi) {
#pragma unroll
            for (int r = 0; r < 4; ++r) {
                const int dbr = mi * 16 + lhalf * 4 + r;   // C/D row = (lane>>4)*4+reg
                const int j = row0 + dbr;
                const float d2 = sql[dbr] + sqq - 2.f * acc[mi][r];
                if (j < rend && j != q) topk_insert<KTH>(bd, bi, d2, j);
            }
        }
    };

    stage(0, 0);
    __syncthreads();
    for (int t = 0; t < nt; ++t) {
        if (t + 1 < nt) stage(t + 1, (t + 1) & 1);
        compute(t, t & 1);
        __syncthreads();
    }

    // ---- merge 4 per-lane lists per query (via LDS, aliases tile buffers) ----
    float* md = (float*)smem;
    int*   mI = (int*)(smem + 256 * KTH * 4);
#pragma unroll
    for (int p = 0; p < KTH; ++p) {
        md[tid * KTH + p] = bd[p];
        mI[tid * KTH + p] = bi[p];
    }
    __syncthreads();
    if (lane < 16) {
        float fd[CAND]; int fi[CAND];
#pragma unroll
        for (int p = 0; p < CAND; ++p) { fd[p] = __builtin_inff(); fi[p] = 0x7fffffff; }
        for (int g = 0; g < 4; ++g) {
            const int src = wid * 64 + g * 16 + lane;
#pragma unroll
            for (int p = 0; p < KTH; ++p)
                topk_insert<CAND>(fd, fi, md[src * KTH + p], mI[src * KTH + p]);
        }
        if (q < n) {
#pragma unroll
            for (int p = 0; p < CAND; ++p)
                cand[((size_t)sp * n + q) * CAND + p] = fi[p];
        }
    }
}

// ---------------- fp64 rescore + exact top-K select ----------------
// One wave per row; lane handles candidates lane and lane+64 (128 total).
template<int D, int K>
__global__ __launch_bounds__(256)
void rescore_kernel(const float* __restrict__ X, const int* __restrict__ cand,
                    int* __restrict__ idx_out, int n) {
    const int lane = threadIdx.x & 63;
    const int row  = blockIdx.x * 4 + (threadIdx.x >> 6);
    if (row >= n) return;

    double d2[2]; int jj[2];
#pragma unroll
    for (int h = 0; h < 2; ++h) {
        const int c = h * 64 + lane;
        const int spc = c >> 4, slot = c & 15;
        int j = cand[((size_t)spc * n + row) * CAND + slot];
        double s = 1e300;
        if (j >= 0 && j < n) {
            const float4* xi = (const float4*)(X + (size_t)row * D);
            const float4* xj = (const float4*)(X + (size_t)j * D);
            double acc = 0.0;
#pragma unroll
            for (int u = 0; u < D / 4; ++u) {
                const float4 a = xi[u];
                const float4 b = xj[u];
                double t;
                t = (double)a.x - (double)b.x; acc = fma(t, t, acc);
                t = (double)a.y - (double)b.y; acc = fma(t, t, acc);
                t = (double)a.z - (double)b.z; acc = fma(t, t, acc);
                t = (double)a.w - (double)b.w; acc = fma(t, t, acc);
            }
            s = acc;
        } else {
            j = 0x7fffffff;
        }
        d2[h] = s; jj[h] = j;
    }

#pragma unroll
    for (int p = 0; p < K; ++p) {
        const bool f = (d2[0] < d2[1]) || ((d2[0] == d2[1]) && (jj[0] < jj[1]));
        double md = f ? d2[0] : d2[1];
        int    mj = f ? jj[0] : jj[1];
#pragma unroll
        for (int off = 32; off >= 1; off >>= 1) {
            const double od = __shfl_xor(md, off, 64);
            const int    oj = __shfl_xor(mj, off, 64);
            if ((od < md) || ((od == md) && (oj < mj))) { md = od; mj = oj; }
        }
        if (lane == 0) idx_out[(size_t)row * K + p] = mj;
        if (jj[0] == mj)      { d2[0] = 1e300; jj[0] = 0x7fffffff; }
        else if (jj[1] == mj) { d2[1] = 1e300; jj[1] = 0x7fffffff; }
    }
}

// ---------------- T = X @ W^T (bias folded into gather-max) ----------------
template<int D>
__global__ __launch_bounds__(256)
void lin_kernel(const float* __restrict__ X, const float* __restrict__ W,
                float* __restrict__ T, int n) {
    constexpr int PB = 16;
    __shared__ float Wlds[D * HID];
    __shared__ float Xlds[PB * D];
    const int tid = threadIdx.x;
    const int p0 = blockIdx.x * PB;

    {
        const int h  = tid & 127;
        const int hf = tid >> 7;
#pragma unroll
        for (int u = 0; u < D / 8; ++u) {
            const int d0 = hf * (D / 2) + u * 4;
            const float4 v = *(const float4*)(W + (size_t)h * D + d0);
            Wlds[(d0 + 0) * HID + h] = v.x;
            Wlds[(d0 + 1) * HID + h] = v.y;
            Wlds[(d0 + 2) * HID + h] = v.z;
            Wlds[(d0 + 3) * HID + h] = v.w;
        }
    }
    {
        const int rr = tid & 15;
        const int g  = tid >> 4;
        constexpr int DG = D / 16;
        const int p = p0 + rr;
        const bool ok = p < n;
#pragma unroll
        for (int u = 0; u < DG / 4; ++u) {
            const int d0 = g * DG + u * 4;
            const float4 v = ok ? *(const float4*)(X + (size_t)p * D + d0)
                                : make_float4(0.f, 0.f, 0.f, 0.f);
            *(float4*)(&Xlds[rr * D + d0]) = v;
        }
    }
    __syncthreads();

    const int pp = tid >> 4;
    const int hh = tid & 15;
    float acc[8];
#pragma unroll
    for (int e = 0; e < 8; ++e) acc[e] = 0.f;
#pragma unroll 4
    for (int d = 0; d < D; ++d) {
        const float xa = Xlds[pp * D + d];
#pragma unroll
        for (int e = 0; e < 8; ++e)
            acc[e] = fmaf(xa, Wlds[d * HID + hh + 16 * e], acc[e]);
    }
    const int p = p0 + pp;
    if (p < n) {
#pragma unroll
        for (int e = 0; e < 8; ++e)
            T[(size_t)p * HID + hh + 16 * e] = acc[e];
    }
}

// ---------------- h[i,:] = max_j T[idx_j,:] - T[i,:] + b ----------------
template<int K>
__global__ void gathermax_kernel(const float* __restrict__ T, const int* __restrict__ idx,
                                 const float* __restrict__ b, float* __restrict__ out, int n) {
    const int i = blockIdx.x;
    const int h = threadIdx.x;
    float m = -__builtin_inff();
#pragma unroll
    for (int t = 0; t < K; ++t) {
        const int j = idx[(size_t)i * K + t];
        m = fmaxf(m, T[(size_t)j * HID + h]);
    }
    out[(size_t)i * HID + h] = m - T[(size_t)i * HID + h] + b[h];
}

// ---------------- out = h2 @ Wl^T + bl ----------------
__global__ void final_kernel(const float* __restrict__ h2, const float* __restrict__ Wl,
                             const float* __restrict__ bl, float* __restrict__ out, int n) {
    const int t = blockIdx.x * 256 + threadIdx.x;
    const int i = t >> 4;
    const int c = t & 15;
    if (i >= n || c >= 10) return;
    const float* hr = h2 + (size_t)i * HID;
    const float* wr = Wl + (size_t)c * HID;
    float s = 0.f;
#pragma unroll 4
    for (int d = 0; d < HID; ++d) s = fmaf(hr[d], wr[d], s);
    out[(size_t)i * 10 + c] = s + bl[c];
}

extern "C" void kernel_launch(void* const* d_in, const int* in_sizes, int n_in,
                              void* d_out, int out_size, void* d_ws, size_t ws_size,
                              hipStream_t stream) {
    const float* x  = (const float*)d_in[0];
    const float* W1 = (const float*)d_in[1];
    const float* b1 = (const float*)d_in[2];
    const float* W2 = (const float*)d_in[3];
    const float* b2 = (const float*)d_in[4];
    const float* Wl = (const float*)d_in[5];
    const float* bl = (const float*)d_in[6];
    float* out = (float*)d_out;
    const int n = in_sizes[0] / 64;   // 10000
    constexpr int K1 = 5, K2 = 10;

    char* ws = (char*)d_ws;
    size_t off = 0;
    auto alloc = [&](size_t bytes) -> void* {
        void* p = ws + off;
        off = (off + bytes + 255) & ~(size_t)255;
        return p;
    };
    float* T1   = (float*)alloc((size_t)n * HID * 4);   // reused as T2
    float* h1b  = (float*)alloc((size_t)n * HID * 4);   // reused as h2b
    float* sqx  = (float*)alloc((size_t)n * 4);
    float* sqh  = (float*)alloc((size_t)n * 4);
    int*   idx1 = (int*)alloc((size_t)n * K1 * 4);
    int*   idx2 = (int*)alloc((size_t)n * K2 * 4);
    int*   ci   = (int*)alloc((size_t)NSPLIT * n * CAND * 4);
    u16*   Xhi  = (u16*)alloc((size_t)n * 64 * 2);
    u16*   Xlo  = (u16*)alloc((size_t)n * 64 * 2);
    u16*   Hhi  = (u16*)alloc((size_t)n * HID * 2);
    u16*   Hlo  = (u16*)alloc((size_t)n * HID * 2);
    float* T2  = T1;
    float* h2b = h1b;

    const int cps = (n + NSPLIT - 1) / NSPLIT;   // 1250
    const int qbs = (n + 63) / 64;               // 157

    // ---- layer 1 (D=64, K=5) ----
    sqnorm_kernel<64><<<(n + 255) / 256, 256, 0, stream>>>(x, sqx, n);
    split_bf16_kernel<<<(n * 64 / 4 + 255) / 256, 256, 0, stream>>>(x, Xhi, Xlo, n * 64 / 4);
    knn_mfma_kernel<64><<<dim3(qbs, NSPLIT), 256, 0, stream>>>(Xhi, Xlo, sqx, ci, n, cps);
    rescore_kernel<64, K1><<<(n + 3) / 4, 256, 0, stream>>>(x, ci, idx1, n);
    lin_kernel<64><<<(n + 15) / 16, 256, 0, stream>>>(x, W1, T1, n);
    gathermax_kernel<K1><<<n, HID, 0, stream>>>(T1, idx1, b1, h1b, n);

    // ---- layer 2 (D=128, K=10) ----
    sqnorm_kernel<HID><<<(n + 255) / 256, 256, 0, stream>>>(h1b, sqh, n);
    split_bf16_kernel<<<(n * HID / 4 + 255) / 256, 256, 0, stream>>>(h1b, Hhi, Hlo, n * HID / 4);
    knn_mfma_kernel<HID><<<dim3(qbs, NSPLIT), 256, 0, stream>>>(Hhi, Hlo, sqh, ci, n, cps);
    rescore_kernel<HID, K2><<<(n + 3) / 4, 256, 0, stream>>>(h1b, ci, idx2, n);
    lin_kernel<HID><<<(n + 15) / 16, 256, 0, stream>>>(h1b, W2, T2, n);
    gathermax_kernel<K2><<<n, HID, 0, stream>>>(T2, idx2, b2, h2b, n);

    // ---- head ----
    final_kernel<<<(n * 16 + 255) / 256, 256, 0, stream>>>(h2b, Wl, bl, out, n);
}